// Round 8
// baseline (427.587 us; speedup 1.0000x reference)
//
#include <hip/hip_runtime.h>

#define D64 64
#define EPS 1e-16f

typedef unsigned int uint;
typedef uint uivec4 __attribute__((ext_vector_type(4)));

__device__ __forceinline__ float bf_lo(uint u) { return __uint_as_float(u << 16); }
__device__ __forceinline__ float bf_hi(uint u) { return __uint_as_float(u & 0xffff0000u); }
__device__ __forceinline__ unsigned short f2bf(float f) {
    uint u = __float_as_uint(f);
    u += 0x7fffu + ((u >> 16) & 1u);     // round-to-nearest-even
    return (unsigned short)(u >> 16);
}
__device__ __forceinline__ float rsum16(float p) {
    p += __shfl_xor(p, 1);
    p += __shfl_xor(p, 2);
    p += __shfl_xor(p, 4);
    p += __shfl_xor(p, 8);
    return p;
}

// note: indexed access (V[0..3]) avoids macro name-capture on .x/.y/.z/.w
#define DEC8(V, h)                                              \
    h[0] = bf_lo(V[0]); h[1] = bf_hi(V[0]);                     \
    h[2] = bf_lo(V[1]); h[3] = bf_hi(V[1]);                     \
    h[4] = bf_lo(V[2]); h[5] = bf_hi(V[2]);                     \
    h[6] = bf_lo(V[3]); h[7] = bf_hi(V[3]);

#define DOT8(a, b) (a[0]*b[0] + a[1]*b[1] + a[2]*b[2] + a[3]*b[3] + \
                    a[4]*b[4] + a[5]*b[5] + a[6]*b[6] + a[7]*b[7])

// ---- kernel 1: q,skip f32 + packed bf16 kv ; fused in-degree histogram ----
__global__ __launch_bounds__(256) void qkvs_kernel(
    const float* __restrict__ x,
    const float* __restrict__ Wq, const float* __restrict__ bq,
    const float* __restrict__ Wk, const float* __restrict__ bk,
    const float* __restrict__ Wv, const float* __restrict__ bv,
    const float* __restrict__ Ws, const float* __restrict__ bs,
    float* __restrict__ q, unsigned short* __restrict__ kv,
    float* __restrict__ skip, int n_nodes,
    const int* __restrict__ dst, int* __restrict__ deg, int E)
{
    __shared__ float wq[4096], wk[4096], wv[4096];
    __shared__ float xs[16 * 64];
    __shared__ float bqs[64], bks[64], bvs[64], bss[64];
    int t = threadIdx.x;
    for (int i = t; i < 1024; i += 256) {
        ((float4*)wq)[i] = ((const float4*)Wq)[i];
        ((float4*)wk)[i] = ((const float4*)Wk)[i];
        ((float4*)wv)[i] = ((const float4*)Wv)[i];
    }
    if (t < 64) { bqs[t] = bq[t]; bks[t] = bk[t]; bvs[t] = bv[t]; bss[t] = bs[t]; }
    __syncthreads();

    int d  = t & 63;
    int j0 = t >> 6;
    int ntiles = (n_nodes + 15) / 16;
    for (int tile = blockIdx.x; tile < ntiles; tile += gridDim.x) {
        int base = tile * 16;
        __syncthreads();
        if (base + 16 <= n_nodes) {
            ((float4*)xs)[t] = ((const float4*)x)[(size_t)base * 16 + t];
        } else {
            for (int i = t; i < 1024; i += 256) {
                int node = base + (i >> 6);
                xs[i] = (node < n_nodes) ? x[(size_t)node * 64 + (i & 63)] : 0.0f;
            }
        }
        __syncthreads();

        float aq[4], ak[4], av[4], asv[4];
        #pragma unroll
        for (int j = 0; j < 4; ++j) { aq[j] = bqs[d]; ak[j] = bks[d]; av[j] = bvs[d]; asv[j] = bss[d]; }
        #pragma unroll 8
        for (int i = 0; i < 64; ++i) {
            float w0 = wq[i * 64 + d];
            float w1 = wk[i * 64 + d];
            float w2 = wv[i * 64 + d];
            float w3 = Ws[i * 64 + d];
            #pragma unroll
            for (int j = 0; j < 4; ++j) {
                float xi = xs[(j0 * 4 + j) * 64 + i];
                aq[j]  += xi * w0;
                ak[j]  += xi * w1;
                av[j]  += xi * w2;
                asv[j] += xi * w3;
            }
        }
        #pragma unroll
        for (int j = 0; j < 4; ++j) {
            int node = base + j0 * 4 + j;
            if (node < n_nodes) {
                size_t o = (size_t)node * 64 + d;
                q[o] = aq[j];
                skip[o] = asv[j];
                unsigned short* row = kv + (size_t)node * 128;
                row[d]      = f2bf(ak[j]);
                row[64 + d] = f2bf(av[j]);
            }
        }
    }

    // fused in-degree histogram
    for (int e = blockIdx.x * 256 + t; e < E; e += gridDim.x * 256)
        atomicAdd(deg + dst[e], 1);
}

// ---- kernel 2: exclusive prefix sum over deg -> rowstart (single block) ----
__global__ __launch_bounds__(1024) void scan_kernel(
    const int* __restrict__ deg, int* __restrict__ rowstart, int N, int E)
{
    __shared__ int sums[1024];
    int t = threadIdx.x;
    int chunk = (N + 1023) >> 10;
    int beg = t * chunk;
    int end = min(beg + chunk, N);
    int s = 0;
    for (int i = beg; i < end; ++i) s += deg[i];
    sums[t] = s;
    __syncthreads();
    for (int off = 1; off < 1024; off <<= 1) {
        int add = (t >= off) ? sums[t - off] : 0;
        __syncthreads();
        sums[t] += add;
        __syncthreads();
    }
    int prefix = (t == 0) ? 0 : sums[t - 1];
    for (int i = beg; i < end; ++i) { rowstart[i] = prefix; prefix += deg[i]; }
    if (t == 0) rowstart[N] = E;
}

// ---- kernel 3: CSR fill — reorder src ids by dst ----
__global__ __launch_bounds__(256) void fill_kernel(
    const int* __restrict__ src, const int* __restrict__ dst,
    const int* __restrict__ rowstart, int* __restrict__ cursor,
    int* __restrict__ srcs, int E)
{
    int e = blockIdx.x * 256 + threadIdx.x;
    if (e >= E) return;
    int d = dst[e];
    int pos = rowstart[d] + atomicAdd(cursor + d, 1);
    srcs[pos] = src[e];
}

// ---- kernel 4: fused attention gather + skip + relu + graph pool ----
// 16 lanes per dst node; one 16B load per lane per edge (packed bf16 k||v).
// Lanes 0-7 carry k-half (and q-slices), lanes 8-15 carry v-half (and acc).
__global__ __launch_bounds__(256) void attn_gather_kernel(
    const float* __restrict__ q, const uint* __restrict__ kv,
    const float* __restrict__ skip,
    const int* __restrict__ rowstart, const int* __restrict__ srcs,
    const int* __restrict__ batch,
    float* __restrict__ out, float* __restrict__ cnt, int N)
{
    int t = threadIdx.x;
    int l = t & 15;
    int node = (blockIdx.x * 256 + t) >> 4;
    bool valid = node < N;

    float q8[8];
    #pragma unroll
    for (int j = 0; j < 8; ++j) q8[j] = 0.f;
    int p0 = 0, p1 = 0;
    if (valid) {
        if (l < 8) {
            float4 a = ((const float4*)q)[(size_t)node * 16 + l * 2 + 0];
            float4 b = ((const float4*)q)[(size_t)node * 16 + l * 2 + 1];
            q8[0] = a.x; q8[1] = a.y; q8[2] = a.z; q8[3] = a.w;
            q8[4] = b.x; q8[5] = b.y; q8[6] = b.z; q8[7] = b.w;
        }
        p0 = rowstart[node];
        p1 = rowstart[node + 1];
    }

    float acc[8];
    #pragma unroll
    for (int j = 0; j < 8; ++j) acc[j] = 0.f;
    float den = 0.f;
    float m = -INFINITY;

    const uivec4* kv4 = (const uivec4*)kv;   // 16 x 16B per node row

    int p = p0;
    for (; p + 4 <= p1; p += 4) {
        int s0 = srcs[p + 0];
        int s1 = srcs[p + 1];
        int s2 = srcs[p + 2];
        int s3 = srcs[p + 3];
        uivec4 w0 = kv4[(size_t)s0 * 16 + l];
        uivec4 w1 = kv4[(size_t)s1 * 16 + l];
        uivec4 w2 = kv4[(size_t)s2 * 16 + l];
        uivec4 w3 = kv4[(size_t)s3 * 16 + l];
        float h0[8], h1[8], h2[8], h3[8];
        DEC8(w0, h0) DEC8(w1, h1) DEC8(w2, h2) DEC8(w3, h3)

        float l0 = rsum16(DOT8(q8, h0)) * 0.125f;
        float l1 = rsum16(DOT8(q8, h1)) * 0.125f;
        float l2 = rsum16(DOT8(q8, h2)) * 0.125f;
        float l3 = rsum16(DOT8(q8, h3)) * 0.125f;

        float mx = fmaxf(fmaxf(l0, l1), fmaxf(l2, l3));
        if (mx > m) {
            float sc = __expf(m - mx);        // first quad: exp(-inf)=0
            den *= sc;
            #pragma unroll
            for (int j = 0; j < 8; ++j) acc[j] *= sc;
            m = mx;
        }
        float e0 = __expf(l0 - m);
        float e1 = __expf(l1 - m);
        float e2 = __expf(l2 - m);
        float e3 = __expf(l3 - m);
        den += (e0 + e1) + (e2 + e3);
        #pragma unroll
        for (int j = 0; j < 8; ++j)
            acc[j] += e0 * h0[j] + e1 * h1[j] + e2 * h2[j] + e3 * h3[j];
    }
    for (; p < p1; ++p) {
        int s = srcs[p];
        uivec4 w0 = kv4[(size_t)s * 16 + l];
        float h0[8];
        DEC8(w0, h0)
        float lg = rsum16(DOT8(q8, h0)) * 0.125f;
        if (lg > m) {
            float sc = __expf(m - lg);
            den *= sc;
            #pragma unroll
            for (int j = 0; j < 8; ++j) acc[j] *= sc;
            m = lg;
        }
        float ev = __expf(lg - m);
        den += ev;
        #pragma unroll
        for (int j = 0; j < 8; ++j) acc[j] += ev * h0[j];
    }

    // epilogue: only lanes 8-15 hold meaningful acc (v-half, dims (l-8)*8 .. +8)
    float o8[8];
    #pragma unroll
    for (int j = 0; j < 8; ++j) o8[j] = 0.f;
    int g = -1;
    if (valid) {
        if (l >= 8) {
            float inv = 1.0f / (den + EPS);        // den==0 -> acc==0 -> 0
            float4 sa = ((const float4*)skip)[(size_t)node * 16 + (l - 8) * 2 + 0];
            float4 sb = ((const float4*)skip)[(size_t)node * 16 + (l - 8) * 2 + 1];
            o8[0] = fmaxf(acc[0] * inv + sa.x, 0.f);
            o8[1] = fmaxf(acc[1] * inv + sa.y, 0.f);
            o8[2] = fmaxf(acc[2] * inv + sa.z, 0.f);
            o8[3] = fmaxf(acc[3] * inv + sa.w, 0.f);
            o8[4] = fmaxf(acc[4] * inv + sb.x, 0.f);
            o8[5] = fmaxf(acc[5] * inv + sb.y, 0.f);
            o8[6] = fmaxf(acc[6] * inv + sb.z, 0.f);
            o8[7] = fmaxf(acc[7] * inv + sb.w, 0.f);
        }
        g = batch[node];
    }

    // wave-level pool: batch sorted => most waves have one graph for all 4 nodes
    int g0 = __shfl(g, 0);
    bool uni = __all(g == g0);
    if (uni) {
        if (g0 >= 0) {
            #pragma unroll
            for (int j = 0; j < 8; ++j) {
                o8[j] += __shfl_xor(o8[j], 16);
                o8[j] += __shfl_xor(o8[j], 32);
            }
            int wl = t & 63;
            if (wl >= 8 && wl < 16) {
                float* o = out + (size_t)g0 * 64 + (l - 8) * 8;
                #pragma unroll
                for (int j = 0; j < 8; ++j) atomicAdd(o + j, o8[j]);
            }
            if (wl == 0) atomicAdd(cnt + g0, 4.0f);
        }
    } else if (valid && l >= 8) {
        float* o = out + (size_t)g * 64 + (l - 8) * 8;
        #pragma unroll
        for (int j = 0; j < 8; ++j) atomicAdd(o + j, o8[j]);
        if (l == 8) atomicAdd(cnt + g, 1.0f);
    }
}

// ---- kernel 5: divide pooled sums by counts ----
__global__ __launch_bounds__(256) void pool_div_kernel(
    float* __restrict__ out, const float* __restrict__ cnt, int n)
{
    int idx = blockIdx.x * 256 + threadIdx.x;
    if (idx >= n) return;
    int g = idx >> 6;
    out[idx] /= fmaxf(cnt[g], 1.0f);
}

extern "C" void kernel_launch(void* const* d_in, const int* in_sizes, int n_in,
                              void* d_out, int out_size, void* d_ws, size_t ws_size,
                              hipStream_t stream) {
    const float* x     = (const float*)d_in[0];
    const int*   eidx  = (const int*)d_in[1];
    const int*   batch = (const int*)d_in[2];
    const float* Wq = (const float*)d_in[3];
    const float* bq = (const float*)d_in[4];
    const float* Wk = (const float*)d_in[5];
    const float* bk = (const float*)d_in[6];
    const float* Wv = (const float*)d_in[7];
    const float* bv = (const float*)d_in[8];
    const float* Ws = (const float*)d_in[9];
    const float* bs = (const float*)d_in[10];

    int N = in_sizes[0] / D64;
    int E = in_sizes[1] / 2;
    const int* src = eidx;
    const int* dst = eidx + E;

    char* w = (char*)d_ws;
    size_t NB = (size_t)N * D64 * sizeof(float);   // 12.8 MB
    float*          q    = (float*)(w);
    float*          skip = (float*)(w + NB);
    unsigned short* kv   = (unsigned short*)(w + 2 * NB);   // N*128 ushorts = NB bytes
    char* p = w + 3 * NB;
    int*   deg      = (int*)p;                 p += (size_t)N * 4;
    int*   cursor   = (int*)p;                 p += (size_t)N * 4;
    int*   rowstart = (int*)p;                 p += (size_t)(N + 1) * 4;
    int*   srcs     = (int*)p;                 p += (size_t)E * 4;
    float* cnt      = (float*)p;

    (void)hipMemsetAsync(deg, 0, 2 * (size_t)N * 4, stream);
    (void)hipMemsetAsync(cnt, 0, 64 * sizeof(float), stream);
    (void)hipMemsetAsync(d_out, 0, (size_t)out_size * sizeof(float), stream);

    qkvs_kernel<<<1024, 256, 0, stream>>>(x, Wq, bq, Wk, bk, Wv, bv, Ws, bs,
                                          q, kv, skip, N, dst, deg, E);
    scan_kernel<<<1, 1024, 0, stream>>>(deg, rowstart, N, E);
    int blocks_e = (E + 255) / 256;
    fill_kernel<<<blocks_e, 256, 0, stream>>>(src, dst, rowstart, cursor, srcs, E);
    int blocks_g = ((size_t)N * 16 + 255) / 256;
    attn_gather_kernel<<<blocks_g, 256, 0, stream>>>(q, (const uint*)kv, skip,
                                                     rowstart, srcs, batch,
                                                     (float*)d_out, cnt, N);
    pool_div_kernel<<<(out_size + 255) / 256, 256, 0, stream>>>((float*)d_out,
                                                                (const float*)cnt, out_size);
}

// Round 9
// 425.049 us; speedup vs baseline: 1.0060x; 1.0060x over previous
//
#include <hip/hip_runtime.h>

#define D64 64
#define EPS 1e-16f

typedef unsigned int uint;
typedef uint uivec4 __attribute__((ext_vector_type(4)));

__device__ __forceinline__ float bf_lo(uint u) { return __uint_as_float(u << 16); }
__device__ __forceinline__ float bf_hi(uint u) { return __uint_as_float(u & 0xffff0000u); }
__device__ __forceinline__ unsigned short f2bf(float f) {
    uint u = __float_as_uint(f);
    u += 0x7fffu + ((u >> 16) & 1u);     // round-to-nearest-even
    return (unsigned short)(u >> 16);
}
__device__ __forceinline__ float rsum16(float p) {
    p += __shfl_xor(p, 1);
    p += __shfl_xor(p, 2);
    p += __shfl_xor(p, 4);
    p += __shfl_xor(p, 8);
    return p;
}

// indexed access (V[0..3]) avoids macro name-capture on .x/.y/.z/.w
#define DEC8(V, h)                                              \
    h[0] = bf_lo(V[0]); h[1] = bf_hi(V[0]);                     \
    h[2] = bf_lo(V[1]); h[3] = bf_hi(V[1]);                     \
    h[4] = bf_lo(V[2]); h[5] = bf_hi(V[2]);                     \
    h[6] = bf_lo(V[3]); h[7] = bf_hi(V[3]);

#define DOT8(a, b) (a[0]*b[0] + a[1]*b[1] + a[2]*b[2] + a[3]*b[3] + \
                    a[4]*b[4] + a[5]*b[5] + a[6]*b[6] + a[7]*b[7])

// ---- kernel 1: q,skip f32 + packed bf16 kv ; fused in-degree histogram ----
__global__ __launch_bounds__(256) void qkvs_kernel(
    const float* __restrict__ x,
    const float* __restrict__ Wq, const float* __restrict__ bq,
    const float* __restrict__ Wk, const float* __restrict__ bk,
    const float* __restrict__ Wv, const float* __restrict__ bv,
    const float* __restrict__ Ws, const float* __restrict__ bs,
    float* __restrict__ q, unsigned short* __restrict__ kv,
    float* __restrict__ skip, int n_nodes,
    const int* __restrict__ dst, int* __restrict__ deg, int E)
{
    __shared__ float wq[4096], wk[4096], wv[4096];
    __shared__ float xs[16 * 64];
    __shared__ float bqs[64], bks[64], bvs[64], bss[64];
    int t = threadIdx.x;
    for (int i = t; i < 1024; i += 256) {
        ((float4*)wq)[i] = ((const float4*)Wq)[i];
        ((float4*)wk)[i] = ((const float4*)Wk)[i];
        ((float4*)wv)[i] = ((const float4*)Wv)[i];
    }
    if (t < 64) { bqs[t] = bq[t]; bks[t] = bk[t]; bvs[t] = bv[t]; bss[t] = bs[t]; }
    __syncthreads();

    int d  = t & 63;
    int j0 = t >> 6;
    int ntiles = (n_nodes + 15) / 16;
    for (int tile = blockIdx.x; tile < ntiles; tile += gridDim.x) {
        int base = tile * 16;
        __syncthreads();
        if (base + 16 <= n_nodes) {
            ((float4*)xs)[t] = ((const float4*)x)[(size_t)base * 16 + t];
        } else {
            for (int i = t; i < 1024; i += 256) {
                int node = base + (i >> 6);
                xs[i] = (node < n_nodes) ? x[(size_t)node * 64 + (i & 63)] : 0.0f;
            }
        }
        __syncthreads();

        float aq[4], ak[4], av[4], asv[4];
        #pragma unroll
        for (int j = 0; j < 4; ++j) { aq[j] = bqs[d]; ak[j] = bks[d]; av[j] = bvs[d]; asv[j] = bss[d]; }
        #pragma unroll 8
        for (int i = 0; i < 64; ++i) {
            float w0 = wq[i * 64 + d];
            float w1 = wk[i * 64 + d];
            float w2 = wv[i * 64 + d];
            float w3 = Ws[i * 64 + d];
            #pragma unroll
            for (int j = 0; j < 4; ++j) {
                float xi = xs[(j0 * 4 + j) * 64 + i];
                aq[j]  += xi * w0;
                ak[j]  += xi * w1;
                av[j]  += xi * w2;
                asv[j] += xi * w3;
            }
        }
        #pragma unroll
        for (int j = 0; j < 4; ++j) {
            int node = base + j0 * 4 + j;
            if (node < n_nodes) {
                size_t o = (size_t)node * 64 + d;
                q[o] = aq[j];
                skip[o] = asv[j];
                unsigned short* row = kv + (size_t)node * 128;
                row[d]      = f2bf(ak[j]);
                row[64 + d] = f2bf(av[j]);
            }
        }
    }

    // fused in-degree histogram
    for (int e = blockIdx.x * 256 + t; e < E; e += gridDim.x * 256)
        atomicAdd(deg + dst[e], 1);
}

// ---- kernel 2: exclusive prefix sum over deg -> rowstart (single block) ----
__global__ __launch_bounds__(1024) void scan_kernel(
    const int* __restrict__ deg, int* __restrict__ rowstart, int N, int E)
{
    __shared__ int sums[1024];
    int t = threadIdx.x;
    int chunk = (N + 1023) >> 10;
    int beg = t * chunk;
    int end = min(beg + chunk, N);
    int s = 0;
    for (int i = beg; i < end; ++i) s += deg[i];
    sums[t] = s;
    __syncthreads();
    for (int off = 1; off < 1024; off <<= 1) {
        int add = (t >= off) ? sums[t - off] : 0;
        __syncthreads();
        sums[t] += add;
        __syncthreads();
    }
    int prefix = (t == 0) ? 0 : sums[t - 1];
    for (int i = beg; i < end; ++i) { rowstart[i] = prefix; prefix += deg[i]; }
    if (t == 0) rowstart[N] = E;
}

// ---- kernel 3: CSR fill — reorder src ids by dst ----
__global__ __launch_bounds__(256) void fill_kernel(
    const int* __restrict__ src, const int* __restrict__ dst,
    const int* __restrict__ rowstart, int* __restrict__ cursor,
    int* __restrict__ srcs, int E)
{
    int e = blockIdx.x * 256 + threadIdx.x;
    if (e >= E) return;
    int d = dst[e];
    int pos = rowstart[d] + atomicAdd(cursor + d, 1);
    srcs[pos] = src[e];
}

// ---- kernel 4: fused attention gather + skip + relu + graph pool ----
// 16 lanes per dst node; packed bf16 k||v row = one 16B load/lane/edge.
// 8-edge deep unroll: all 8 gathers issued before any consumption (8KB/wave
// in flight), consumed as two 4-edge halves to cap decoded-register live range.
__global__ __launch_bounds__(256) void attn_gather_kernel(
    const float* __restrict__ q, const uint* __restrict__ kv,
    const float* __restrict__ skip,
    const int* __restrict__ rowstart, const int* __restrict__ srcs,
    const int* __restrict__ batch,
    float* __restrict__ out, float* __restrict__ cnt, int N)
{
    int t = threadIdx.x;
    int l = t & 15;
    int node = (blockIdx.x * 256 + t) >> 4;
    bool valid = node < N;

    float q8[8];
    #pragma unroll
    for (int j = 0; j < 8; ++j) q8[j] = 0.f;
    int p0 = 0, p1 = 0;
    if (valid) {
        if (l < 8) {
            float4 a = ((const float4*)q)[(size_t)node * 16 + l * 2 + 0];
            float4 b = ((const float4*)q)[(size_t)node * 16 + l * 2 + 1];
            q8[0] = a.x; q8[1] = a.y; q8[2] = a.z; q8[3] = a.w;
            q8[4] = b.x; q8[5] = b.y; q8[6] = b.z; q8[7] = b.w;
        }
        p0 = rowstart[node];
        p1 = rowstart[node + 1];
    }

    float acc[8];
    #pragma unroll
    for (int j = 0; j < 8; ++j) acc[j] = 0.f;
    float den = 0.f;
    float m = -INFINITY;

    const uivec4* kv4 = (const uivec4*)kv;   // 16 x 16B per node row

    int p = p0;
    // ---- 8-edge deep-unrolled main loop ----
    for (; p + 8 <= p1; p += 8) {
        int s0 = srcs[p + 0]; int s1 = srcs[p + 1];
        int s2 = srcs[p + 2]; int s3 = srcs[p + 3];
        int s4 = srcs[p + 4]; int s5 = srcs[p + 5];
        int s6 = srcs[p + 6]; int s7 = srcs[p + 7];
        // issue ALL 8 independent gathers before any use
        uivec4 w0 = kv4[(size_t)s0 * 16 + l];
        uivec4 w1 = kv4[(size_t)s1 * 16 + l];
        uivec4 w2 = kv4[(size_t)s2 * 16 + l];
        uivec4 w3 = kv4[(size_t)s3 * 16 + l];
        uivec4 w4 = kv4[(size_t)s4 * 16 + l];
        uivec4 w5 = kv4[(size_t)s5 * 16 + l];
        uivec4 w6 = kv4[(size_t)s6 * 16 + l];
        uivec4 w7 = kv4[(size_t)s7 * 16 + l];

        // ---- half A: edges 0-3 (gathers 4-7 still in flight) ----
        {
            float h0[8], h1[8], h2[8], h3[8];
            DEC8(w0, h0) DEC8(w1, h1) DEC8(w2, h2) DEC8(w3, h3)
            float l0 = rsum16(DOT8(q8, h0)) * 0.125f;
            float l1 = rsum16(DOT8(q8, h1)) * 0.125f;
            float l2 = rsum16(DOT8(q8, h2)) * 0.125f;
            float l3 = rsum16(DOT8(q8, h3)) * 0.125f;
            float mx = fmaxf(fmaxf(l0, l1), fmaxf(l2, l3));
            if (mx > m) {
                float sc = __expf(m - mx);    // first quad: exp(-inf)=0
                den *= sc;
                #pragma unroll
                for (int j = 0; j < 8; ++j) acc[j] *= sc;
                m = mx;
            }
            float e0 = __expf(l0 - m);
            float e1 = __expf(l1 - m);
            float e2 = __expf(l2 - m);
            float e3 = __expf(l3 - m);
            den += (e0 + e1) + (e2 + e3);
            #pragma unroll
            for (int j = 0; j < 8; ++j)
                acc[j] += e0 * h0[j] + e1 * h1[j] + e2 * h2[j] + e3 * h3[j];
        }
        // ---- half B: edges 4-7 ----
        {
            float h0[8], h1[8], h2[8], h3[8];
            DEC8(w4, h0) DEC8(w5, h1) DEC8(w6, h2) DEC8(w7, h3)
            float l0 = rsum16(DOT8(q8, h0)) * 0.125f;
            float l1 = rsum16(DOT8(q8, h1)) * 0.125f;
            float l2 = rsum16(DOT8(q8, h2)) * 0.125f;
            float l3 = rsum16(DOT8(q8, h3)) * 0.125f;
            float mx = fmaxf(fmaxf(l0, l1), fmaxf(l2, l3));
            if (mx > m) {
                float sc = __expf(m - mx);
                den *= sc;
                #pragma unroll
                for (int j = 0; j < 8; ++j) acc[j] *= sc;
                m = mx;
            }
            float e0 = __expf(l0 - m);
            float e1 = __expf(l1 - m);
            float e2 = __expf(l2 - m);
            float e3 = __expf(l3 - m);
            den += (e0 + e1) + (e2 + e3);
            #pragma unroll
            for (int j = 0; j < 8; ++j)
                acc[j] += e0 * h0[j] + e1 * h1[j] + e2 * h2[j] + e3 * h3[j];
        }
    }
    // ---- 4-edge tail ----
    for (; p + 4 <= p1; p += 4) {
        int s0 = srcs[p + 0]; int s1 = srcs[p + 1];
        int s2 = srcs[p + 2]; int s3 = srcs[p + 3];
        uivec4 w0 = kv4[(size_t)s0 * 16 + l];
        uivec4 w1 = kv4[(size_t)s1 * 16 + l];
        uivec4 w2 = kv4[(size_t)s2 * 16 + l];
        uivec4 w3 = kv4[(size_t)s3 * 16 + l];
        float h0[8], h1[8], h2[8], h3[8];
        DEC8(w0, h0) DEC8(w1, h1) DEC8(w2, h2) DEC8(w3, h3)
        float l0 = rsum16(DOT8(q8, h0)) * 0.125f;
        float l1 = rsum16(DOT8(q8, h1)) * 0.125f;
        float l2 = rsum16(DOT8(q8, h2)) * 0.125f;
        float l3 = rsum16(DOT8(q8, h3)) * 0.125f;
        float mx = fmaxf(fmaxf(l0, l1), fmaxf(l2, l3));
        if (mx > m) {
            float sc = __expf(m - mx);
            den *= sc;
            #pragma unroll
            for (int j = 0; j < 8; ++j) acc[j] *= sc;
            m = mx;
        }
        float e0 = __expf(l0 - m);
        float e1 = __expf(l1 - m);
        float e2 = __expf(l2 - m);
        float e3 = __expf(l3 - m);
        den += (e0 + e1) + (e2 + e3);
        #pragma unroll
        for (int j = 0; j < 8; ++j)
            acc[j] += e0 * h0[j] + e1 * h1[j] + e2 * h2[j] + e3 * h3[j];
    }
    // ---- scalar tail ----
    for (; p < p1; ++p) {
        int s = srcs[p];
        uivec4 w0 = kv4[(size_t)s * 16 + l];
        float h0[8];
        DEC8(w0, h0)
        float lg = rsum16(DOT8(q8, h0)) * 0.125f;
        if (lg > m) {
            float sc = __expf(m - lg);
            den *= sc;
            #pragma unroll
            for (int j = 0; j < 8; ++j) acc[j] *= sc;
            m = lg;
        }
        float ev = __expf(lg - m);
        den += ev;
        #pragma unroll
        for (int j = 0; j < 8; ++j) acc[j] += ev * h0[j];
    }

    // epilogue: only lanes 8-15 hold meaningful acc (v-half, dims (l-8)*8 .. +8)
    float o8[8];
    #pragma unroll
    for (int j = 0; j < 8; ++j) o8[j] = 0.f;
    int g = -1;
    if (valid) {
        if (l >= 8) {
            float inv = 1.0f / (den + EPS);        // den==0 -> acc==0 -> 0
            float4 sa = ((const float4*)skip)[(size_t)node * 16 + (l - 8) * 2 + 0];
            float4 sb = ((const float4*)skip)[(size_t)node * 16 + (l - 8) * 2 + 1];
            o8[0] = fmaxf(acc[0] * inv + sa.x, 0.f);
            o8[1] = fmaxf(acc[1] * inv + sa.y, 0.f);
            o8[2] = fmaxf(acc[2] * inv + sa.z, 0.f);
            o8[3] = fmaxf(acc[3] * inv + sa.w, 0.f);
            o8[4] = fmaxf(acc[4] * inv + sb.x, 0.f);
            o8[5] = fmaxf(acc[5] * inv + sb.y, 0.f);
            o8[6] = fmaxf(acc[6] * inv + sb.z, 0.f);
            o8[7] = fmaxf(acc[7] * inv + sb.w, 0.f);
        }
        g = batch[node];
    }

    // wave-level pool: batch sorted => most waves have one graph for all 4 nodes
    int g0 = __shfl(g, 0);
    bool uni = __all(g == g0);
    if (uni) {
        if (g0 >= 0) {
            #pragma unroll
            for (int j = 0; j < 8; ++j) {
                o8[j] += __shfl_xor(o8[j], 16);
                o8[j] += __shfl_xor(o8[j], 32);
            }
            int wl = t & 63;
            if (wl >= 8 && wl < 16) {
                float* o = out + (size_t)g0 * 64 + (l - 8) * 8;
                #pragma unroll
                for (int j = 0; j < 8; ++j) atomicAdd(o + j, o8[j]);
            }
            if (wl == 0) atomicAdd(cnt + g0, 4.0f);
        }
    } else if (valid && l >= 8) {
        float* o = out + (size_t)g * 64 + (l - 8) * 8;
        #pragma unroll
        for (int j = 0; j < 8; ++j) atomicAdd(o + j, o8[j]);
        if (l == 8) atomicAdd(cnt + g, 1.0f);
    }
}

// ---- kernel 5: divide pooled sums by counts ----
__global__ __launch_bounds__(256) void pool_div_kernel(
    float* __restrict__ out, const float* __restrict__ cnt, int n)
{
    int idx = blockIdx.x * 256 + threadIdx.x;
    if (idx >= n) return;
    int g = idx >> 6;
    out[idx] /= fmaxf(cnt[g], 1.0f);
}

extern "C" void kernel_launch(void* const* d_in, const int* in_sizes, int n_in,
                              void* d_out, int out_size, void* d_ws, size_t ws_size,
                              hipStream_t stream) {
    const float* x     = (const float*)d_in[0];
    const int*   eidx  = (const int*)d_in[1];
    const int*   batch = (const int*)d_in[2];
    const float* Wq = (const float*)d_in[3];
    const float* bq = (const float*)d_in[4];
    const float* Wk = (const float*)d_in[5];
    const float* bk = (const float*)d_in[6];
    const float* Wv = (const float*)d_in[7];
    const float* bv = (const float*)d_in[8];
    const float* Ws = (const float*)d_in[9];
    const float* bs = (const float*)d_in[10];

    int N = in_sizes[0] / D64;
    int E = in_sizes[1] / 2;
    const int* src = eidx;
    const int* dst = eidx + E;

    char* w = (char*)d_ws;
    size_t NB = (size_t)N * D64 * sizeof(float);   // 12.8 MB
    float*          q    = (float*)(w);
    float*          skip = (float*)(w + NB);
    unsigned short* kv   = (unsigned short*)(w + 2 * NB);   // N*128 ushorts = NB bytes
    char* p = w + 3 * NB;
    int*   deg      = (int*)p;                 p += (size_t)N * 4;
    int*   cursor   = (int*)p;                 p += (size_t)N * 4;
    float* cnt      = (float*)p;               p += 64 * 4;
    int*   rowstart = (int*)p;                 p += (size_t)(N + 1) * 4;
    int*   srcs     = (int*)p;

    // deg + cursor + cnt are contiguous -> one memset
    (void)hipMemsetAsync(deg, 0, (2 * (size_t)N + 64) * 4, stream);
    (void)hipMemsetAsync(d_out, 0, (size_t)out_size * sizeof(float), stream);

    qkvs_kernel<<<1024, 256, 0, stream>>>(x, Wq, bq, Wk, bk, Wv, bv, Ws, bs,
                                          q, kv, skip, N, dst, deg, E);
    scan_kernel<<<1, 1024, 0, stream>>>(deg, rowstart, N, E);
    int blocks_e = (E + 255) / 256;
    fill_kernel<<<blocks_e, 256, 0, stream>>>(src, dst, rowstart, cursor, srcs, E);
    int blocks_g = ((size_t)N * 16 + 255) / 256;
    attn_gather_kernel<<<blocks_g, 256, 0, stream>>>(q, (const uint*)kv, skip,
                                                     rowstart, srcs, batch,
                                                     (float*)d_out, cnt, N);
    pool_div_kernel<<<(out_size + 255) / 256, 256, 0, stream>>>((float*)d_out,
                                                                (const float*)cnt, out_size);
}

// Round 11
// 403.305 us; speedup vs baseline: 1.0602x; 1.0539x over previous
//
#include <hip/hip_runtime.h>

#define D64 64
#define EPS 1e-16f

typedef unsigned int uint;
typedef uint uivec2 __attribute__((ext_vector_type(2)));

__device__ __forceinline__ float bf_lo(uint u) { return __uint_as_float(u << 16); }
__device__ __forceinline__ float bf_hi(uint u) { return __uint_as_float(u & 0xffff0000u); }
__device__ __forceinline__ unsigned short f2bf(float f) {
    uint u = __float_as_uint(f);
    u += 0x7fffu + ((u >> 16) & 1u);     // round-to-nearest-even
    return (unsigned short)(u >> 16);
}
__device__ __forceinline__ float rsum16(float p) {
    p += __shfl_xor(p, 1);
    p += __shfl_xor(p, 2);
    p += __shfl_xor(p, 4);
    p += __shfl_xor(p, 8);
    return p;
}
// dot of lane's 4 q dims with 4 bf16 values packed in uivec2
__device__ __forceinline__ float dotk(float4 q4, uivec2 w) {
    return q4.x * bf_lo(w[0]) + q4.y * bf_hi(w[0]) +
           q4.z * bf_lo(w[1]) + q4.w * bf_hi(w[1]);
}

// ---- kernel 1: q,skip f32 + separate bf16 k,v buffers ; fused histogram ----
__global__ __launch_bounds__(256) void qkvs_kernel(
    const float* __restrict__ x,
    const float* __restrict__ Wq, const float* __restrict__ bq,
    const float* __restrict__ Wk, const float* __restrict__ bk,
    const float* __restrict__ Wv, const float* __restrict__ bv,
    const float* __restrict__ Ws, const float* __restrict__ bs,
    float* __restrict__ q, unsigned short* __restrict__ kbuf,
    unsigned short* __restrict__ vbuf,
    float* __restrict__ skip, int n_nodes,
    const int* __restrict__ dst, int* __restrict__ deg, int E)
{
    __shared__ float wq[4096], wk[4096], wv[4096];
    __shared__ float xs[16 * 64];
    __shared__ float bqs[64], bks[64], bvs[64], bss[64];
    int t = threadIdx.x;
    for (int i = t; i < 1024; i += 256) {
        ((float4*)wq)[i] = ((const float4*)Wq)[i];
        ((float4*)wk)[i] = ((const float4*)Wk)[i];
        ((float4*)wv)[i] = ((const float4*)Wv)[i];
    }
    if (t < 64) { bqs[t] = bq[t]; bks[t] = bk[t]; bvs[t] = bv[t]; bss[t] = bs[t]; }
    __syncthreads();

    int d  = t & 63;
    int j0 = t >> 6;
    int ntiles = (n_nodes + 15) / 16;
    for (int tile = blockIdx.x; tile < ntiles; tile += gridDim.x) {
        int base = tile * 16;
        __syncthreads();
        if (base + 16 <= n_nodes) {
            ((float4*)xs)[t] = ((const float4*)x)[(size_t)base * 16 + t];
        } else {
            for (int i = t; i < 1024; i += 256) {
                int node = base + (i >> 6);
                xs[i] = (node < n_nodes) ? x[(size_t)node * 64 + (i & 63)] : 0.0f;
            }
        }
        __syncthreads();

        float aq[4], ak[4], av[4], asv[4];
        #pragma unroll
        for (int j = 0; j < 4; ++j) { aq[j] = bqs[d]; ak[j] = bks[d]; av[j] = bvs[d]; asv[j] = bss[d]; }
        #pragma unroll 8
        for (int i = 0; i < 64; ++i) {
            float w0 = wq[i * 64 + d];
            float w1 = wk[i * 64 + d];
            float w2 = wv[i * 64 + d];
            float w3 = Ws[i * 64 + d];
            #pragma unroll
            for (int j = 0; j < 4; ++j) {
                float xi = xs[(j0 * 4 + j) * 64 + i];
                aq[j]  += xi * w0;
                ak[j]  += xi * w1;
                av[j]  += xi * w2;
                asv[j] += xi * w3;
            }
        }
        #pragma unroll
        for (int j = 0; j < 4; ++j) {
            int node = base + j0 * 4 + j;
            if (node < n_nodes) {
                size_t o = (size_t)node * 64 + d;
                q[o]    = aq[j];
                skip[o] = asv[j];
                kbuf[o] = f2bf(ak[j]);
                vbuf[o] = f2bf(av[j]);
            }
        }
    }

    // fused in-degree histogram
    for (int e = blockIdx.x * 256 + t; e < E; e += gridDim.x * 256)
        atomicAdd(deg + dst[e], 1);
}

// ---- kernel 2: exclusive prefix sum over deg -> rowstart (single block) ----
__global__ __launch_bounds__(1024) void scan_kernel(
    const int* __restrict__ deg, int* __restrict__ rowstart, int N, int E)
{
    __shared__ int sums[1024];
    int t = threadIdx.x;
    int chunk = (N + 1023) >> 10;
    int beg = t * chunk;
    int end = min(beg + chunk, N);
    int s = 0;
    for (int i = beg; i < end; ++i) s += deg[i];
    sums[t] = s;
    __syncthreads();
    for (int off = 1; off < 1024; off <<= 1) {
        int add = (t >= off) ? sums[t - off] : 0;
        __syncthreads();
        sums[t] += add;
        __syncthreads();
    }
    int prefix = (t == 0) ? 0 : sums[t - 1];
    for (int i = beg; i < end; ++i) { rowstart[i] = prefix; prefix += deg[i]; }
    if (t == 0) rowstart[N] = E;
}

// ---- kernel 3: CSR fill — reorder src ids by dst ----
__global__ __launch_bounds__(256) void fill_kernel(
    const int* __restrict__ src, const int* __restrict__ dst,
    const int* __restrict__ rowstart, int* __restrict__ cursor,
    int* __restrict__ srcs, int E)
{
    int e = blockIdx.x * 256 + threadIdx.x;
    if (e >= E) return;
    int d = dst[e];
    int pos = rowstart[d] + atomicAdd(cursor + d, 1);
    srcs[pos] = src[e];
}

// ---- kernel 4 (pass A): k-gather -> logits, running max m, denom den ----
// 16 lanes per dst node; 128B (2 lines) gathered per edge from the 6.4MB kbuf.
__global__ __launch_bounds__(256) void qk_logits_kernel(
    const float* __restrict__ q, const uint* __restrict__ kbuf,
    const int* __restrict__ rowstart, const int* __restrict__ srcs,
    float* __restrict__ logits, float* __restrict__ mden, int N)
{
    int t = threadIdx.x;
    int l = t & 15;
    int node = (blockIdx.x * 256 + t) >> 4;
    bool valid = node < N;

    float4 q4 = make_float4(0.f, 0.f, 0.f, 0.f);
    int p0 = 0, p1 = 0;
    if (valid) {
        q4 = ((const float4*)q)[(size_t)node * 16 + l];
        p0 = rowstart[node];
        p1 = rowstart[node + 1];
    }

    float m = -INFINITY, den = 0.f;
    const uivec2* k2 = (const uivec2*)kbuf;   // 16 x 8B per node row

    int p = p0;
    for (; p + 4 <= p1; p += 4) {
        int s0 = srcs[p + 0]; int s1 = srcs[p + 1];
        int s2 = srcs[p + 2]; int s3 = srcs[p + 3];
        uivec2 w0 = k2[(size_t)s0 * 16 + l];
        uivec2 w1 = k2[(size_t)s1 * 16 + l];
        uivec2 w2 = k2[(size_t)s2 * 16 + l];
        uivec2 w3 = k2[(size_t)s3 * 16 + l];
        float l0 = rsum16(dotk(q4, w0)) * 0.125f;
        float l1 = rsum16(dotk(q4, w1)) * 0.125f;
        float l2 = rsum16(dotk(q4, w2)) * 0.125f;
        float l3 = rsum16(dotk(q4, w3)) * 0.125f;
        float mx = fmaxf(fmaxf(l0, l1), fmaxf(l2, l3));
        if (mx > m) {
            den *= __expf(m - mx);     // first quad: exp(-inf)=0
            m = mx;
        }
        den += __expf(l0 - m) + __expf(l1 - m) + __expf(l2 - m) + __expf(l3 - m);
        if (l < 4) {
            float lv = (l == 0) ? l0 : (l == 1) ? l1 : (l == 2) ? l2 : l3;
            logits[p + l] = lv;
        }
    }
    for (; p < p1; ++p) {
        int s = srcs[p];
        uivec2 w0 = k2[(size_t)s * 16 + l];
        float lg = rsum16(dotk(q4, w0)) * 0.125f;
        if (lg > m) {
            den *= __expf(m - lg);
            m = lg;
        }
        den += __expf(lg - m);
        if (l == 0) logits[p] = lg;
    }

    if (valid && l == 0) {
        mden[2 * (size_t)node + 0] = m;
        mden[2 * (size_t)node + 1] = den;
    }
}

// ---- kernel 5 (pass B): v-gather -> out = relu(sum(e*v)/den + skip), pool ----
__global__ __launch_bounds__(256) void pv_kernel(
    const uint* __restrict__ vbuf, const float* __restrict__ skip,
    const float* __restrict__ logits, const float* __restrict__ mden,
    const int* __restrict__ rowstart, const int* __restrict__ srcs,
    const int* __restrict__ batch,
    float* __restrict__ out, float* __restrict__ cnt, int N)
{
    int t = threadIdx.x;
    int l = t & 15;
    int node = (blockIdx.x * 256 + t) >> 4;
    bool valid = node < N;

    int p0 = 0, p1 = 0;
    float m = 0.f, den = 0.f;
    if (valid) {
        p0 = rowstart[node];
        p1 = rowstart[node + 1];
        m   = mden[2 * (size_t)node + 0];
        den = mden[2 * (size_t)node + 1];
    }

    float4 acc = make_float4(0.f, 0.f, 0.f, 0.f);
    const uivec2* v2 = (const uivec2*)vbuf;

    int p = p0;
    for (; p + 4 <= p1; p += 4) {
        int s0 = srcs[p + 0]; int s1 = srcs[p + 1];
        int s2 = srcs[p + 2]; int s3 = srcs[p + 3];
        uivec2 w0 = v2[(size_t)s0 * 16 + l];
        uivec2 w1 = v2[(size_t)s1 * 16 + l];
        uivec2 w2 = v2[(size_t)s2 * 16 + l];
        uivec2 w3 = v2[(size_t)s3 * 16 + l];
        float e0 = __expf(logits[p + 0] - m);
        float e1 = __expf(logits[p + 1] - m);
        float e2 = __expf(logits[p + 2] - m);
        float e3 = __expf(logits[p + 3] - m);
        acc.x += e0 * bf_lo(w0[0]) + e1 * bf_lo(w1[0]) + e2 * bf_lo(w2[0]) + e3 * bf_lo(w3[0]);
        acc.y += e0 * bf_hi(w0[0]) + e1 * bf_hi(w1[0]) + e2 * bf_hi(w2[0]) + e3 * bf_hi(w3[0]);
        acc.z += e0 * bf_lo(w0[1]) + e1 * bf_lo(w1[1]) + e2 * bf_lo(w2[1]) + e3 * bf_lo(w3[1]);
        acc.w += e0 * bf_hi(w0[1]) + e1 * bf_hi(w1[1]) + e2 * bf_hi(w2[1]) + e3 * bf_hi(w3[1]);
    }
    for (; p < p1; ++p) {
        int s = srcs[p];
        uivec2 w0 = v2[(size_t)s * 16 + l];
        float ev = __expf(logits[p] - m);
        acc.x += ev * bf_lo(w0[0]);
        acc.y += ev * bf_hi(w0[0]);
        acc.z += ev * bf_lo(w0[1]);
        acc.w += ev * bf_hi(w0[1]);
    }

    float4 val = make_float4(0.f, 0.f, 0.f, 0.f);
    int g = -1;
    if (valid) {
        float inv = 1.0f / (den + EPS);          // deg 0 -> acc=0 -> 0
        float4 sk = ((const float4*)skip)[(size_t)node * 16 + l];
        val.x = fmaxf(acc.x * inv + sk.x, 0.f);
        val.y = fmaxf(acc.y * inv + sk.y, 0.f);
        val.z = fmaxf(acc.z * inv + sk.z, 0.f);
        val.w = fmaxf(acc.w * inv + sk.w, 0.f);
        g = batch[node];
    }

    // wave-level pool: batch sorted => most waves have one graph for all 4 nodes
    int g0 = __shfl(g, 0);
    bool uni = __all(g == g0);
    if (uni) {
        if (g0 >= 0) {
            val.x += __shfl_xor(val.x, 16); val.x += __shfl_xor(val.x, 32);
            val.y += __shfl_xor(val.y, 16); val.y += __shfl_xor(val.y, 32);
            val.z += __shfl_xor(val.z, 16); val.z += __shfl_xor(val.z, 32);
            val.w += __shfl_xor(val.w, 16); val.w += __shfl_xor(val.w, 32);
            if ((t & 63) < 16) {
                float* o = out + (size_t)g0 * 64 + l * 4;
                atomicAdd(o + 0, val.x);
                atomicAdd(o + 1, val.y);
                atomicAdd(o + 2, val.z);
                atomicAdd(o + 3, val.w);
            }
            if ((t & 63) == 0) atomicAdd(cnt + g0, 4.0f);
        }
    } else if (valid) {
        float* o = out + (size_t)g * 64 + l * 4;
        atomicAdd(o + 0, val.x);
        atomicAdd(o + 1, val.y);
        atomicAdd(o + 2, val.z);
        atomicAdd(o + 3, val.w);
        if (l == 0) atomicAdd(cnt + g, 1.0f);
    }
}

// ---- kernel 6: divide pooled sums by counts ----
__global__ __launch_bounds__(256) void pool_div_kernel(
    float* __restrict__ out, const float* __restrict__ cnt, int n)
{
    int idx = blockIdx.x * 256 + threadIdx.x;
    if (idx >= n) return;
    int g = idx >> 6;
    out[idx] /= fmaxf(cnt[g], 1.0f);
}

extern "C" void kernel_launch(void* const* d_in, const int* in_sizes, int n_in,
                              void* d_out, int out_size, void* d_ws, size_t ws_size,
                              hipStream_t stream) {
    const float* x     = (const float*)d_in[0];
    const int*   eidx  = (const int*)d_in[1];
    const int*   batch = (const int*)d_in[2];
    const float* Wq = (const float*)d_in[3];
    const float* bq = (const float*)d_in[4];
    const float* Wk = (const float*)d_in[5];
    const float* bk = (const float*)d_in[6];
    const float* Wv = (const float*)d_in[7];
    const float* bv = (const float*)d_in[8];
    const float* Ws = (const float*)d_in[9];
    const float* bs = (const float*)d_in[10];

    int N = in_sizes[0] / D64;
    int E = in_sizes[1] / 2;
    const int* src = eidx;
    const int* dst = eidx + E;

    char* w = (char*)d_ws;
    size_t NB = (size_t)N * D64 * sizeof(float);   // 12.8 MB
    float*          q    = (float*)(w);
    float*          skip = (float*)(w + NB);
    unsigned short* kbuf = (unsigned short*)(w + 2 * NB);            // 6.4 MB
    unsigned short* vbuf = (unsigned short*)(w + 2 * NB + NB / 2);   // 6.4 MB
    char* p = w + 3 * NB;
    float* logits   = (float*)p;               p += (size_t)E * 4;
    float* mden     = (float*)p;               p += 2 * (size_t)N * 4;
    int*   deg      = (int*)p;                 p += (size_t)N * 4;
    int*   cursor   = (int*)p;                 p += (size_t)N * 4;
    float* cnt      = (float*)p;               p += 64 * 4;
    int*   rowstart = (int*)p;                 p += (size_t)(N + 1) * 4;
    int*   srcs     = (int*)p;

    // deg + cursor + cnt are contiguous -> one memset
    (void)hipMemsetAsync(deg, 0, (2 * (size_t)N + 64) * 4, stream);
    (void)hipMemsetAsync(d_out, 0, (size_t)out_size * sizeof(float), stream);

    qkvs_kernel<<<1024, 256, 0, stream>>>(x, Wq, bq, Wk, bk, Wv, bv, Ws, bs,
                                          q, kbuf, vbuf, skip, N, dst, deg, E);
    scan_kernel<<<1, 1024, 0, stream>>>(deg, rowstart, N, E);
    int blocks_e = (E + 255) / 256;
    fill_kernel<<<blocks_e, 256, 0, stream>>>(src, dst, rowstart, cursor, srcs, E);
    int blocks_g = ((size_t)N * 16 + 255) / 256;
    qk_logits_kernel<<<blocks_g, 256, 0, stream>>>(q, (const uint*)kbuf, rowstart,
                                                   srcs, logits, mden, N);
    pv_kernel<<<blocks_g, 256, 0, stream>>>((const uint*)vbuf, skip, logits, mden,
                                            rowstart, srcs, batch,
                                            (float*)d_out, cnt, N);
    pool_div_kernel<<<(out_size + 255) / 256, 256, 0, stream>>>((float*)d_out,
                                                                (const float*)cnt, out_size);
}